// Round 12
// baseline (793.296 us; speedup 1.0000x reference)
//
#include <hip/hip_runtime.h>
#include <hip/hip_bf16.h>

typedef __attribute__((ext_vector_type(4))) short short4_t;
typedef __attribute__((ext_vector_type(4))) float f32x4;

constexpr int NMB = 256;

#if __has_builtin(__builtin_amdgcn_mfma_f32_16x16x16bf16_1k)
#define MFMA16(a, b, c) __builtin_amdgcn_mfma_f32_16x16x16bf16_1k(a, b, c, 0, 0, 0)
#else
__device__ inline f32x4 mfma16_asm(short4_t a, short4_t b, f32x4 c) {
    asm volatile("v_mfma_f32_16x16x16_bf16 %0, %1, %2, %0\n\ts_nop 7\n\ts_nop 7"
                 : "+v"(c) : "v"(a), "v"(b));
    return c;
}
#define MFMA16(a, b, c) mfma16_asm(a, b, c)
#endif

#define TR_READ(dst, addr, IMM) \
    asm volatile("ds_read_b64_tr_b16 %0, %1 offset:" IMM : "=&v"(dst) : "v"(addr) : "memory")

union U2S4 { unsigned u[2]; short4_t s; };
union FI { float f; int i; };

__device__ inline unsigned pkbf(float a, float b) {
    union { __hip_bfloat162 h; unsigned u; } c;
    c.h = __float22bfloat162_rn(make_float2(a, b));
    return c.u;
}
__device__ inline short bf16s(float x) { return (short)(pkbf(x, 0.f) & 0xffffu); }
__device__ inline short4_t pk4(float a, float b, float c, float d) {
    U2S4 u; u.u[0] = pkbf(a, b); u.u[1] = pkbf(c, d); return u.s;
}
// all-VALU 16-lane sum reduce (within each 16-lane DPP row)
__device__ inline float dpp16(float x) {
    FI v; v.f = x; FI t;
    t.i = __builtin_amdgcn_update_dpp(0, v.i, 0xB1, 0xf, 0xf, true);  v.f += t.f;
    t.i = __builtin_amdgcn_update_dpp(0, v.i, 0x4E, 0xf, 0xf, true);  v.f += t.f;
    t.i = __builtin_amdgcn_update_dpp(0, v.i, 0x124, 0xf, 0xf, true); v.f += t.f;
    t.i = __builtin_amdgcn_update_dpp(0, v.i, 0x128, 0xf, 0xf, true); v.f += t.f;
    return v.f;
}

__global__ __launch_bounds__(64) void ttt_scan(
    const float* __restrict__ gXQ, const float* __restrict__ gXK,
    const float* __restrict__ gXV, const float* __restrict__ gETA,
    const float* __restrict__ gW1, const float* __restrict__ gB1,
    const float* __restrict__ gLNW, const float* __restrict__ gLNB,
    float* __restrict__ gOUT)
{
    __shared__ __align__(16) short sXKe[1024];   // xk^T in tr-tiles (bf16), staged 1 step ahead
    __shared__ __align__(16) short sE[16 * 20];  // -E [s][j], stride 20
    __shared__ __align__(16) float sEta[2][256]; // parity-buffered eta tile

    const int l = threadIdx.x;
    const int G = l >> 4, l15 = l & 15;
    const int bh = blockIdx.x, b = bh >> 3, h = bh & 7;

    const float* xqg = gXQ + (size_t)bh * (NMB * 1024);
    const float* xkg = gXK + (size_t)bh * (NMB * 1024);
    const float* xvg = gXV + (size_t)bh * (NMB * 1024);
    const float* etg = gETA + (size_t)bh * (NMB * 256);

    // LN params: per-lane scalars (depend only on col = 16nt + l15)
    float gaC[4], betC[4], c1C[4], gbC[4];
#pragma unroll
    for (int nt = 0; nt < 4; ++nt) {
        gaC[nt]  = gLNW[h * 64 + 16 * nt + l15];
        betC[nt] = gLNB[h * 64 + 16 * nt + l15];
        c1C[nt]  = gaC[nt] * gaC[nt];
        gbC[nt]  = gaC[nt] * betC[nt];
    }
    const float sc1 = dpp16(c1C[0] + c1C[1] + c1C[2] + c1C[3]);

    // W state: full matrix as 16 C-fragments (C layout == B layout, k==row)
    f32x4 Wacc[4][4];
    short4_t WB[4][4];
#pragma unroll
    for (int kt = 0; kt < 4; ++kt)
#pragma unroll
        for (int nt = 0; nt < 4; ++nt) {
#pragma unroll
            for (int r = 0; r < 4; ++r)
                Wacc[kt][nt][r] = gW1[h * 4096 + (16 * kt + 4 * G + r) * 64 + 16 * nt + l15];
            WB[kt][nt] = pk4(Wacc[kt][nt][0], Wacc[kt][nt][1], Wacc[kt][nt][2], Wacc[kt][nt][3]);
        }
    f32x4 b1v;
#pragma unroll
    for (int nt = 0; nt < 4; ++nt) b1v[nt] = gB1[h * 64 + 16 * nt + l15];

    U2S4 ones_;
    ones_.u[0] = 0x3F803F80u; ones_.u[1] = 0x3F803F80u;
    const short4_t onesA = ones_.s;

    // ---- m=0: A-frag loads (lane l: row l15, cols 16kt+4G..+3) ----
    short4_t ak[4], aq[4];
#pragma unroll
    for (int kt = 0; kt < 4; ++kt) {
        const f32x4 fk = *(const f32x4*)&xkg[l15 * 64 + 16 * kt + 4 * G];
        const f32x4 fq = *(const f32x4*)&xqg[l15 * 64 + 16 * kt + 4 * G];
        ak[kt] = pk4(fk[0], fk[1], fk[2], fk[3]);
        aq[kt] = pk4(fq[0], fq[1], fq[2], fq[3]);
    }
    // stage xk^T tiles for step 0
#pragma unroll
    for (int kt = 0; kt < 4; ++kt)
        *(short4_t*)&sXKe[(l15 >> 2) * 256 + kt * 64 + (l15 & 3) * 16 + 4 * G] = ak[kt];
    // C-layout loads (lane l: row 4G+r, col 16nt+l15)
    float xkC[4][4], xvC[4][4], xqC[4][4];
#pragma unroll
    for (int r = 0; r < 4; ++r)
#pragma unroll
        for (int nt = 0; nt < 4; ++nt) {
            xkC[r][nt] = xkg[(4 * G + r) * 64 + 16 * nt + l15];
            xvC[r][nt] = xvg[(4 * G + r) * 64 + 16 * nt + l15];
            xqC[r][nt] = xqg[(4 * G + r) * 64 + 16 * nt + l15];
        }
    // eta(0) -> sEta[0]; prefetch eta(1), A-frag floats for m=1
    {
        const f32x4 e0 = *(const f32x4*)&etg[l * 4];
        *(f32x4*)&sEta[0][l * 4] = e0;
    }
    f32x4 etaF = *(const f32x4*)&etg[256 + l * 4];
    f32x4 fkn[4], fqn[4];
#pragma unroll
    for (int kt = 0; kt < 4; ++kt) {
        fkn[kt] = *(const f32x4*)&xkg[1024 + l15 * 64 + 16 * kt + 4 * G];
        fqn[kt] = *(const f32x4*)&xqg[1024 + l15 * 64 + 16 * kt + 4 * G];
    }

#pragma unroll 1
    for (int m = 0; m < NMB; ++m) {
        const int p = m & 1;

        // ===== MFMA group 1: Z1 = xk@W + b1 ; Zq = xq@W + b1 ; Attn =====
        f32x4 z1[4], zq[4];
#pragma unroll
        for (int nt = 0; nt < 4; ++nt) {
            f32x4 c0; c0[0] = b1v[nt]; c0[1] = b1v[nt]; c0[2] = b1v[nt]; c0[3] = b1v[nt];
            f32x4 a_ = c0, q_ = c0;
#pragma unroll
            for (int kt = 0; kt < 4; ++kt) a_ = MFMA16(ak[kt], WB[kt][nt], a_);
#pragma unroll
            for (int kt = 0; kt < 4; ++kt) q_ = MFMA16(aq[kt], WB[kt][nt], q_);
            z1[nt] = a_; zq[nt] = q_;
        }
        f32x4 at; at[0] = 0.f; at[1] = 0.f; at[2] = 0.f; at[3] = 0.f;
#pragma unroll
        for (int kt = 0; kt < 4; ++kt) at = MFMA16(aq[kt], ak[kt], at);

        // ===== LN-bwd, fully in-register (row s=4G+r lives in this 16-lane group) =====
        const f32x4 lef = *(const f32x4*)&sEta[p][240 + 4 * G];
        float mu[4], rs[4];
#pragma unroll
        for (int r = 0; r < 4; ++r) {
            const float s1 = dpp16(z1[0][r] + z1[1][r] + z1[2][r] + z1[3][r]);
            const float s2 = dpp16(z1[0][r]*z1[0][r] + z1[1][r]*z1[1][r]
                                 + z1[2][r]*z1[2][r] + z1[3][r]*z1[3][r]);
            mu[r] = s1 * (1.f / 64.f);
            rs[r] = rsqrtf(s2 * (1.f / 64.f) - mu[r] * mu[r] + 1e-6f);
        }
        float gx[4][4], r1[4], r2[4];
#pragma unroll
        for (int r = 0; r < 4; ++r) {
            float p1 = 0.f, p2 = 0.f;
#pragma unroll
            for (int nt = 0; nt < 4; ++nt) {
                const float xh = (z1[nt][r] - mu[r]) * rs[r];
                const float t2 = gbC[nt] - gaC[nt] * (xvC[r][nt] - xkC[r][nt]);
                const float gg = fmaf(c1C[nt], xh, t2);
                gx[r][nt] = gg;
                p1 += gg; p2 = fmaf(gg, xh, p2);
            }
            r1[r] = dpp16(p1); r2[r] = dpp16(p2);
        }
        float gt[4][4];
#pragma unroll
        for (int r = 0; r < 4; ++r) {
            const float cf = rs[r] * (1.f / 64.f);
#pragma unroll
            for (int nt = 0; nt < 4; ++nt) {
                const float xh = (z1[nt][r] - mu[r]) * rs[r];
                gt[r][nt] = (fmaf(64.f, gx[r][nt], -r1[r]) - xh * r2[r]) * cf;
            }
        }
        // g as B-frags directly (C layout == B layout); gle = -le * g
        short4_t g_b[4], gle_b[4];
#pragma unroll
        for (int nt = 0; nt < 4; ++nt) {
            g_b[nt]   = pk4(gt[0][nt], gt[1][nt], gt[2][nt], gt[3][nt]);
            gle_b[nt] = pk4(-lef[0] * gt[0][nt], -lef[1] * gt[1][nt],
                            -lef[2] * gt[2][nt], -lef[3] * gt[3][nt]);
        }

        // reissue xk/xv C-layout loads for m+1 (xk tile m+1 is L2-warm from fkn)
        if (m + 1 < NMB) {
            const size_t o = (size_t)(m + 1) * 1024;
#pragma unroll
            for (int r = 0; r < 4; ++r)
#pragma unroll
                for (int nt = 0; nt < 4; ++nt) {
                    xkC[r][nt] = xkg[o + (4 * G + r) * 64 + 16 * nt + l15];
                    xvC[r][nt] = xvg[o + (4 * G + r) * 64 + 16 * nt + l15];
                }
        }

        // ===== E build (Attn C-frag -> sE, LDS transpose) =====
#pragma unroll
        for (int r = 0; r < 4; ++r) {
            const float ev = sEta[p][(4 * G + r) * 16 + l15];
            const float e = (l15 <= 4 * G + r) ? -ev * (1.f + at[r]) : 0.f;
            sE[(4 * G + r) * 20 + l15] = bf16s(e);
        }
        asm volatile("s_waitcnt lgkmcnt(0)" ::: "memory");
        __builtin_amdgcn_sched_barrier(0);

        // xk^T A-frags via tr-read (staged last step); aE via b64
        const unsigned kb = (unsigned)(size_t)&sXKe[0] + 512u * G + 8u * l15;
        short4_t aXK0, aXK1, aXK2, aXK3;
        TR_READ(aXK0, kb, "0");
        TR_READ(aXK1, kb, "128");
        TR_READ(aXK2, kb, "256");
        TR_READ(aXK3, kb, "384");
        const short4_t aE = *(const short4_t*)&sE[l15 * 20 + 4 * G];
        asm volatile("s_waitcnt lgkmcnt(0)" ::: "memory");
        __builtin_amdgcn_sched_barrier(0);

        // ===== MFMA group 2: W += xk^T@(-le*g) ; Zb = Zq - E@g ; b1 update =====
#pragma unroll
        for (int nt = 0; nt < 4; ++nt) {
            Wacc[0][nt] = MFMA16(aXK0, gle_b[nt], Wacc[0][nt]);
            Wacc[1][nt] = MFMA16(aXK1, gle_b[nt], Wacc[1][nt]);
            Wacc[2][nt] = MFMA16(aXK2, gle_b[nt], Wacc[2][nt]);
            Wacc[3][nt] = MFMA16(aXK3, gle_b[nt], Wacc[3][nt]);
        }
        f32x4 zb[4];
#pragma unroll
        for (int nt = 0; nt < 4; ++nt) {
            zb[nt] = MFMA16(aE, g_b[nt], zq[nt]);
            f32x4 d0; d0[0] = 0.f; d0[1] = 0.f; d0[2] = 0.f; d0[3] = 0.f;
            d0 = MFMA16(onesA, gle_b[nt], d0);
            b1v[nt] += d0[0];
        }
        // repack W -> bf16 B-frags for next step's MFMA1
#pragma unroll
        for (int kt = 0; kt < 4; ++kt)
#pragma unroll
            for (int nt = 0; nt < 4; ++nt)
                WB[kt][nt] = pk4(Wacc[kt][nt][0], Wacc[kt][nt][1],
                                 Wacc[kt][nt][2], Wacc[kt][nt][3]);

        // ===== LN-fwd + output (in-register) =====
        float mu2[4], rs2[4];
#pragma unroll
        for (int r = 0; r < 4; ++r) {
            const float t1 = dpp16(zb[0][r] + zb[1][r] + zb[2][r] + zb[3][r]);
            const float t2 = dpp16(zb[0][r]*zb[0][r] + zb[1][r]*zb[1][r]
                                 + zb[2][r]*zb[2][r] + zb[3][r]*zb[3][r]);
            mu2[r] = t1 * (1.f / 64.f);
            rs2[r] = rsqrtf(t2 * (1.f / 64.f) - mu2[r] * mu2[r] + 1e-6f);
        }
#pragma unroll
        for (int r = 0; r < 4; ++r) {
            const size_t ob = ((size_t)b * 4096 + (size_t)m * 16 + 4 * G + r) * 512 + h * 64 + l15;
#pragma unroll
            for (int nt = 0; nt < 4; ++nt)
                gOUT[ob + 16 * nt] =
                    xqC[r][nt] + fmaf(gaC[nt], (zb[nt][r] - mu2[r]) * rs2[r], betC[nt]);
        }
        // reissue xq C-layout loads for m+1
        if (m + 1 < NMB) {
            const size_t o = (size_t)(m + 1) * 1024;
#pragma unroll
            for (int r = 0; r < 4; ++r)
#pragma unroll
                for (int nt = 0; nt < 4; ++nt)
                    xqC[r][nt] = xqg[o + (4 * G + r) * 64 + 16 * nt + l15];
        }

        // ===== stage m+1: A-frags, xk^T tiles, eta =====
        if (m + 1 < NMB) {
#pragma unroll
            for (int kt = 0; kt < 4; ++kt) {
                ak[kt] = pk4(fkn[kt][0], fkn[kt][1], fkn[kt][2], fkn[kt][3]);
                aq[kt] = pk4(fqn[kt][0], fqn[kt][1], fqn[kt][2], fqn[kt][3]);
                *(short4_t*)&sXKe[(l15 >> 2) * 256 + kt * 64 + (l15 & 3) * 16 + 4 * G] = ak[kt];
            }
            *(f32x4*)&sEta[p ^ 1][l * 4] = etaF;
            if (m + 2 < NMB) {
                const size_t o2 = (size_t)(m + 2) * 1024;
#pragma unroll
                for (int kt = 0; kt < 4; ++kt) {
                    fkn[kt] = *(const f32x4*)&xkg[o2 + l15 * 64 + 16 * kt + 4 * G];
                    fqn[kt] = *(const f32x4*)&xqg[o2 + l15 * 64 + 16 * kt + 4 * G];
                }
                etaF = *(const f32x4*)&etg[(size_t)(m + 2) * 256 + l * 4];
            }
        }
    }
}

extern "C" void kernel_launch(void* const* d_in, const int* in_sizes, int n_in,
                              void* d_out, int out_size, void* d_ws, size_t ws_size,
                              hipStream_t stream) {
    const float* XQ  = (const float*)d_in[0];
    const float* XK  = (const float*)d_in[1];
    const float* XV  = (const float*)d_in[2];
    const float* ETA = (const float*)d_in[3];
    const float* W1  = (const float*)d_in[4];
    const float* B1  = (const float*)d_in[5];
    const float* LNW = (const float*)d_in[6];
    const float* LNB = (const float*)d_in[7];
    float* OUT = (float*)d_out;

    const int n_chains = in_sizes[0] / (NMB * 1024);   // B*nh = 64
    ttt_scan<<<n_chains, 64, 0, stream>>>(XQ, XK, XV, ETA, W1, B1, LNW, LNB, OUT);
}

// Round 13
// 454.203 us; speedup vs baseline: 1.7466x; 1.7466x over previous
//
#include <hip/hip_runtime.h>
#include <hip/hip_bf16.h>

typedef __attribute__((ext_vector_type(4))) short short4_t;
typedef __attribute__((ext_vector_type(4))) float f32x4;

constexpr int NMB = 256;

#if __has_builtin(__builtin_amdgcn_mfma_f32_16x16x16bf16_1k)
#define MFMA16(a, b, c) __builtin_amdgcn_mfma_f32_16x16x16bf16_1k(a, b, c, 0, 0, 0)
#else
__device__ inline f32x4 mfma16_asm(short4_t a, short4_t b, f32x4 c) {
    asm volatile("v_mfma_f32_16x16x16_bf16 %0, %1, %2, %0\n\ts_nop 7\n\ts_nop 7"
                 : "+v"(c) : "v"(a), "v"(b));
    return c;
}
#define MFMA16(a, b, c) mfma16_asm(a, b, c)
#endif

#define TR_READ(dst, addr, IMM) \
    asm volatile("ds_read_b64_tr_b16 %0, %1 offset:" IMM : "=&v"(dst) : "v"(addr) : "memory")

union U2S4 { unsigned u[2]; short4_t s; };
union FI { float f; int i; };

__device__ inline unsigned pkbf(float a, float b) {
    union { __hip_bfloat162 h; unsigned u; } c;
    c.h = __float22bfloat162_rn(make_float2(a, b));
    return c.u;
}
__device__ inline short bf16s(float x) { return (short)(pkbf(x, 0.f) & 0xffffu); }
__device__ inline short4_t pk4(float a, float b, float c, float d) {
    U2S4 u; u.u[0] = pkbf(a, b); u.u[1] = pkbf(c, d); return u.s;
}
// all-VALU 16-lane sum reduce: quad_perm xor1, xor2, then row_ror 4, 8
__device__ inline float dpp16(float x) {
    FI v; v.f = x; FI t;
    t.i = __builtin_amdgcn_update_dpp(0, v.i, 0xB1, 0xf, 0xf, true);  v.f += t.f;
    t.i = __builtin_amdgcn_update_dpp(0, v.i, 0x4E, 0xf, 0xf, true);  v.f += t.f;
    t.i = __builtin_amdgcn_update_dpp(0, v.i, 0x124, 0xf, 0xf, true); v.f += t.f;
    t.i = __builtin_amdgcn_update_dpp(0, v.i, 0x128, 0xf, 0xf, true); v.f += t.f;
    return v.f;
}
// raw barrier: LDS writes visible, global loads stay in flight
__device__ inline void bar() {
    __builtin_amdgcn_sched_barrier(0);
    asm volatile("s_waitcnt lgkmcnt(0)" ::: "memory");
    __builtin_amdgcn_s_barrier();
    __builtin_amdgcn_sched_barrier(0);
}

__global__ __launch_bounds__(256) void ttt_scan(
    const float* __restrict__ gXQ, const float* __restrict__ gXK,
    const float* __restrict__ gXV, const float* __restrict__ gETA,
    const float* __restrict__ gW1, const float* __restrict__ gB1,
    const float* __restrict__ gLNW, const float* __restrict__ gLNB,
    float* __restrict__ gOUT)
{
    __shared__ __align__(16) short sGt[1024];      // g, K=16 4x16 tr-tiles [jblk][nblk]
    __shared__ __align__(16) short sXKe[1024];     // -le*xk, same tiling
    __shared__ __align__(16) short sE[16 * 20];    // -E [r][j], row stride 20
    __shared__ __align__(16) float sZ1[16 * 68];
    __shared__ __align__(16) float sZb[16 * 68];
    __shared__ __align__(16) float sEta[2][256];   // parity-buffered

    const int t  = threadIdx.x;
    const int s  = t >> 4;
    const int dt = t & 15;
    const int lane = t & 63;
    const int w  = t >> 6;
    const int G  = lane >> 4;
    const int l15 = lane & 15;
    const int bh = blockIdx.x, b = bh >> 3, h = bh & 7;

    const float* xqg = gXQ + (size_t)bh * (NMB * 1024);
    const float* xkg = gXK + (size_t)bh * (NMB * 1024);
    const float* xvg = gXV + (size_t)bh * (NMB * 1024);
    const float* etg = gETA + (size_t)bh * (NMB * 256);

    // W state: wave w owns COLUMNS [16w,16w+16) as 4 k-tile C-fragments.
    // C layout == B layout (k==row), so WB[kt] is directly MFMA1's B-operand.
    f32x4 Wacc[4]; short4_t WB[4];
#pragma unroll
    for (int kt = 0; kt < 4; ++kt) {
#pragma unroll
        for (int r = 0; r < 4; ++r)
            Wacc[kt][r] = gW1[h * 4096 + (16 * kt + 4 * G + r) * 64 + 16 * w + l15];
        WB[kt] = pk4(Wacc[kt][0], Wacc[kt][1], Wacc[kt][2], Wacc[kt][3]);
    }
    // b1 state: register, wave w owns col 16w+l15
    float b1v = gB1[h * 64 + 16 * w + l15];

    // LN params in thread layout (phase B + deferred output)
    const float4 gam = *(const float4*)&gLNW[h * 64 + dt * 4];
    const float4 bet = *(const float4*)&gLNB[h * 64 + dt * 4];
    const float ga[4] = {gam.x, gam.y, gam.z, gam.w};
    const float ba[4] = {bet.x, bet.y, bet.z, bet.w};
    float c1a[4], gba[4];
    float sc1 = 0.f;
#pragma unroll
    for (int c = 0; c < 4; ++c) {
        c1a[c] = ga[c] * ga[c];
        gba[c] = ga[c] * ba[c];
        sc1 += c1a[c];
    }
    sc1 = dpp16(sc1);

    // ---- prologue: minibatch 0 ----
    float4 pq = *(const float4*)&xqg[t * 4];
    float4 pk = *(const float4*)&xkg[t * 4];
    float4 pv = *(const float4*)&xvg[t * 4];
    float4 pe = make_float4(0.f, 0.f, 0.f, 0.f);
    if (t < 64) pe = *(const float4*)&etg[t * 4];
    if (t < 64) *(float4*)&sEta[0][t * 4] = pe;

    // A-frags for m=0 (wave layout: lane row l15, cols 16kt+4G..+3)
    short4_t ak[4], aq[4];
#pragma unroll
    for (int kt = 0; kt < 4; ++kt) {
        const f32x4 fk = *(const f32x4*)&xkg[l15 * 64 + 16 * kt + 4 * G];
        const f32x4 fq = *(const f32x4*)&xqg[l15 * 64 + 16 * kt + 4 * G];
        ak[kt] = pk4(fk[0], fk[1], fk[2], fk[3]);
        aq[kt] = pk4(fq[0], fq[1], fq[2], fq[3]);
    }
    f32x4 fkn[4], fqn[4];

    float t2c[4];
    {
        const float pva[4] = {pv.x, pv.y, pv.z, pv.w};
        const float pka_[4] = {pk.x, pk.y, pk.z, pk.w};
#pragma unroll
        for (int c = 0; c < 4; ++c)
            t2c[c] = fmaf(-ga[c], pva[c] - pka_[c], gba[c]);
    }
    float4 pkc = pk;        // xk(m) for phase B's sXKe
    float4 pq_out = pq;     // xq(m) for output
    float4 pq_prev_out;

    __syncthreads();

#pragma unroll 1
    for (int m = 0; m < NMB; ++m) {
        const int p = m & 1;

        // ======== PHASE A: MFMA1 + E build + deferred output; issue prefetch ========
        if (m + 1 < NMB) {
            const size_t o = (size_t)(m + 1) * 1024 + t * 4;
            pq = *(const float4*)&xqg[o];
            pk = *(const float4*)&xkg[o];
            pv = *(const float4*)&xvg[o];
            if (t < 64) pe = *(const float4*)&etg[(size_t)(m + 1) * 256 + t * 4];
            const size_t ow = (size_t)(m + 1) * 1024 + l15 * 64 + 4 * G;
#pragma unroll
            for (int kt = 0; kt < 4; ++kt) {
                fkn[kt] = *(const f32x4*)&xkg[ow + 16 * kt];
                fqn[kt] = *(const f32x4*)&xqg[ow + 16 * kt];
            }
        }

        // Z1/Zq n-tile w from register WB (no LDS!)
        f32x4 z1, zq;
        z1[0]=b1v; z1[1]=b1v; z1[2]=b1v; z1[3]=b1v;
        zq = z1;
#pragma unroll
        for (int kt = 0; kt < 4; ++kt) z1 = MFMA16(ak[kt], WB[kt], z1);
#pragma unroll
        for (int kt = 0; kt < 4; ++kt) zq = MFMA16(aq[kt], WB[kt], zq);
#pragma unroll
        for (int r = 0; r < 4; ++r) sZ1[(4 * G + r) * 68 + 16 * w + l15] = z1[r];

        // wave 3: Attn C-frag -> -E straight to sE
        if (w == 3) {
            f32x4 at; at[0]=0.f; at[1]=0.f; at[2]=0.f; at[3]=0.f;
#pragma unroll
            for (int kt = 0; kt < 4; ++kt) at = MFMA16(aq[kt], ak[kt], at);
#pragma unroll
            for (int r = 0; r < 4; ++r) {
                const int row = 4 * G + r;
                const float ev = sEta[p][row * 16 + l15];
                const float x = (l15 <= row) ? -ev * (1.f + at[r]) : 0.f;
                sE[row * 20 + l15] = bf16s(x);
            }
        }

        // deferred LN-fwd + output for step m-1
        if (m > 0) {
            f32x4 zbr = *(f32x4*)&sZb[s * 68 + dt * 4];
            float T1 = 0.f, T2 = 0.f;
#pragma unroll
            for (int c = 0; c < 4; ++c) { T1 += zbr[c]; T2 = fmaf(zbr[c], zbr[c], T2); }
            T1 = dpp16(T1); T2 = dpp16(T2);
            const float mu2   = T1 * (1.f / 64.f);
            const float rstd2 = rsqrtf(T2 * (1.f / 64.f) - mu2 * mu2 + 1e-6f);
            const float pqa[4] = {pq_prev_out.x, pq_prev_out.y, pq_prev_out.z, pq_prev_out.w};
            float o[4];
#pragma unroll
            for (int c = 0; c < 4; ++c)
                o[c] = pqa[c] + fmaf(ga[c], (zbr[c] - mu2) * rstd2, ba[c]);
            const size_t oi = ((size_t)b * 4096 + (size_t)(m - 1) * 16 + s) * 512 + h * 64 + dt * 4;
            *(float4*)&gOUT[oi] = make_float4(o[0], o[1], o[2], o[3]);
        }
        bar();   // (C) sZ1, sE visible

        // ======== PHASE B: LN-bwd (DPP 6-sum) -> g ; stage g^T, xke^T ========
        f32x4 z = *(f32x4*)&sZ1[s * 68 + dt * 4];
        float S1=0.f,S2=0.f,S3=0.f,S4=0.f,S5=0.f,S6=0.f;
#pragma unroll
        for (int c = 0; c < 4; ++c) {
            const float zc = z[c], c1z = c1a[c] * zc, t2 = t2c[c];
            S1 += zc;  S2 = fmaf(zc, zc, S2);
            S3 += c1z; S4 = fmaf(c1z, zc, S4);
            S5 += t2;  S6 = fmaf(t2, zc, S6);
        }
        S1 = dpp16(S1); S2 = dpp16(S2); S3 = dpp16(S3);
        S4 = dpp16(S4); S5 = dpp16(S5); S6 = dpp16(S6);
        const float mu   = S1 * (1.f / 64.f);
        const float rstd = rsqrtf(S2 * (1.f / 64.f) - mu * mu + 1e-6f);
        const float r1 = rstd * (S3 - mu * sc1) + S5;
        const float r2 = rstd * rstd * (S4 - 2.f * mu * S3 + mu * mu * sc1)
                       + rstd * (S6 - mu * S5);
        const float cf = rstd * (1.f / 64.f);
        float g[4];
#pragma unroll
        for (int c = 0; c < 4; ++c) {
            const float xh = (z[c] - mu) * rstd;
            const float gx = fmaf(c1a[c], xh, t2c[c]);
            g[c] = (fmaf(64.f, gx, -r1) - xh * r2) * cf;
        }
        const float le = sEta[p][240 + s];
        const int tb = (s >> 2) * 256 + (dt >> 2) * 64 + (s & 3) * 16 + (dt & 3) * 4;
        { U2S4 gp; gp.u[0]=pkbf(g[0],g[1]); gp.u[1]=pkbf(g[2],g[3]);
          *(short4_t*)&sGt[tb] = gp.s; }
        { U2S4 kp; kp.u[0]=pkbf(-le*pkc.x,-le*pkc.y); kp.u[1]=pkbf(-le*pkc.z,-le*pkc.w);
          *(short4_t*)&sXKe[tb] = kp.s; }
        bar();   // (D) sGt/sXKe visible

        // ======== PHASE C: W/b1/Zb updates + next-step A-frag packs ========
        const unsigned kbX = (unsigned)(size_t)&sXKe[0] + 512u * G + 8u * l15;
        const unsigned kbG = (unsigned)(size_t)&sGt[0] + 512u * G + 128u * (unsigned)w + 8u * l15;
        short4_t aXK0, aXK1, aXK2, aXK3, bg;
        TR_READ(aXK0, kbX, "0");
        TR_READ(aXK1, kbX, "128");
        TR_READ(aXK2, kbX, "256");
        TR_READ(aXK3, kbX, "384");
        TR_READ(bg,   kbG, "0");
        const short4_t aE = *(const short4_t*)&sE[l15 * 20 + 4 * G];
        const f32x4 lv = *(const f32x4*)&sEta[p][240 + 4 * G];
        U2S4 aL;
        aL.u[0] = pkbf(-lv[0], -lv[1]);
        aL.u[1] = pkbf(-lv[2], -lv[3]);
        asm volatile("s_waitcnt lgkmcnt(0)" ::: "memory");
        __builtin_amdgcn_sched_barrier(0);

        Wacc[0] = MFMA16(aXK0, bg, Wacc[0]);
        Wacc[1] = MFMA16(aXK1, bg, Wacc[1]);
        Wacc[2] = MFMA16(aXK2, bg, Wacc[2]);
        Wacc[3] = MFMA16(aXK3, bg, Wacc[3]);
        f32x4 zb = MFMA16(aE, bg, zq);
        {
            f32x4 d0; d0[0]=0.f; d0[1]=0.f; d0[2]=0.f; d0[3]=0.f;
            d0 = MFMA16(aL.s, bg, d0);
            b1v += d0[0];
        }
        // repack W C-frags -> B-frags in registers (no LDS round-trip)
#pragma unroll
        for (int kt = 0; kt < 4; ++kt)
            WB[kt] = pk4(Wacc[kt][0], Wacc[kt][1], Wacc[kt][2], Wacc[kt][3]);
#pragma unroll
        for (int r = 0; r < 4; ++r) sZb[(4 * G + r) * 68 + 16 * w + l15] = zb[r];

        // stage m+1: A-frag packs, eta, t2c
        if (m + 1 < NMB) {
#pragma unroll
            for (int kt = 0; kt < 4; ++kt) {
                ak[kt] = pk4(fkn[kt][0], fkn[kt][1], fkn[kt][2], fkn[kt][3]);
                aq[kt] = pk4(fqn[kt][0], fqn[kt][1], fqn[kt][2], fqn[kt][3]);
            }
            if (t < 64) *(float4*)&sEta[p ^ 1][t * 4] = pe;
#pragma unroll
            for (int c = 0; c < 4; ++c) {
                const float pva[4] = {pv.x, pv.y, pv.z, pv.w};
                const float pka_[4] = {pk.x, pk.y, pk.z, pk.w};
                t2c[c] = fmaf(-ga[c], pva[c] - pka_[c], gba[c]);
            }
            pkc = pk;
        }
        pq_prev_out = pq_out;
        pq_out = pq;
        bar();   // (E) sZb/sEta visible
    }

    // epilogue: deferred output for m = NMB-1
    {
        f32x4 zbr = *(f32x4*)&sZb[s * 68 + dt * 4];
        float T1 = 0.f, T2 = 0.f;
#pragma unroll
        for (int c = 0; c < 4; ++c) { T1 += zbr[c]; T2 = fmaf(zbr[c], zbr[c], T2); }
        T1 = dpp16(T1); T2 = dpp16(T2);
        const float mu2   = T1 * (1.f / 64.f);
        const float rstd2 = rsqrtf(T2 * (1.f / 64.f) - mu2 * mu2 + 1e-6f);
        const float pqa[4] = {pq_prev_out.x, pq_prev_out.y, pq_prev_out.z, pq_prev_out.w};
        float o[4];
#pragma unroll
        for (int c = 0; c < 4; ++c)
            o[c] = pqa[c] + fmaf(ga[c], (zbr[c] - mu2) * rstd2, ba[c]);
        const size_t oi = ((size_t)b * 4096 + (size_t)(NMB - 1) * 16 + s) * 512 + h * 64 + dt * 4;
        *(float4*)&gOUT[oi] = make_float4(o[0], o[1], o[2], o[3]);
    }
}

extern "C" void kernel_launch(void* const* d_in, const int* in_sizes, int n_in,
                              void* d_out, int out_size, void* d_ws, size_t ws_size,
                              hipStream_t stream) {
    const float* XQ  = (const float*)d_in[0];
    const float* XK  = (const float*)d_in[1];
    const float* XV  = (const float*)d_in[2];
    const float* ETA = (const float*)d_in[3];
    const float* W1  = (const float*)d_in[4];
    const float* B1  = (const float*)d_in[5];
    const float* LNW = (const float*)d_in[6];
    const float* LNB = (const float*)d_in[7];
    float* OUT = (float*)d_out;

    const int n_chains = in_sizes[0] / (NMB * 1024);   // B*nh = 64
    ttt_scan<<<n_chains, 256, 0, stream>>>(XQ, XK, XV, ETA, W1, B1, LNW, LNB, OUT);
}

// Round 14
// 376.553 us; speedup vs baseline: 2.1067x; 1.2062x over previous
//
#include <hip/hip_runtime.h>
#include <hip/hip_bf16.h>

typedef __attribute__((ext_vector_type(8))) short short8;
typedef __attribute__((ext_vector_type(4))) short short4_t;
typedef __attribute__((ext_vector_type(4))) float f32x4;

constexpr int NMB = 256;

#if __has_builtin(__builtin_amdgcn_mfma_f32_16x16x16bf16_1k)
#define MFMA16(a, b, c) __builtin_amdgcn_mfma_f32_16x16x16bf16_1k(a, b, c, 0, 0, 0)
#else
__device__ inline f32x4 mfma16_asm(short4_t a, short4_t b, f32x4 c) {
    asm volatile("v_mfma_f32_16x16x16_bf16 %0, %1, %2, %0\n\ts_nop 7\n\ts_nop 7"
                 : "+v"(c) : "v"(a), "v"(b));
    return c;
}
#define MFMA16(a, b, c) mfma16_asm(a, b, c)
#endif

#define TR_READ(dst, addr, IMM) \
    asm volatile("ds_read_b64_tr_b16 %0, %1 offset:" IMM : "=&v"(dst) : "v"(addr) : "memory")

union U2S4 { unsigned u[2]; short4_t s; };
union FI { float f; int i; };

__device__ inline unsigned pkbf(float a, float b) {
    union { __hip_bfloat162 h; unsigned u; } c;
    c.h = __float22bfloat162_rn(make_float2(a, b));
    return c.u;
}
__device__ inline short bf16s(float x) { return (short)(pkbf(x, 0.f) & 0xffffu); }
__device__ inline short4_t pk4(float a, float b, float c, float d) {
    U2S4 u; u.u[0] = pkbf(a, b); u.u[1] = pkbf(c, d); return u.s;
}
// all-VALU 16-lane sum reduce: quad_perm xor1, xor2, then row_ror 4, 8
__device__ inline float dpp16(float x) {
    FI v; v.f = x; FI t;
    t.i = __builtin_amdgcn_update_dpp(0, v.i, 0xB1, 0xf, 0xf, true);  v.f += t.f;
    t.i = __builtin_amdgcn_update_dpp(0, v.i, 0x4E, 0xf, 0xf, true);  v.f += t.f;
    t.i = __builtin_amdgcn_update_dpp(0, v.i, 0x124, 0xf, 0xf, true); v.f += t.f;
    t.i = __builtin_amdgcn_update_dpp(0, v.i, 0x128, 0xf, 0xf, true); v.f += t.f;
    return v.f;
}
// raw barrier: LDS writes visible, global loads stay in flight
__device__ inline void bar() {
    __builtin_amdgcn_sched_barrier(0);
    asm volatile("s_waitcnt lgkmcnt(0)" ::: "memory");
    __builtin_amdgcn_s_barrier();
    __builtin_amdgcn_sched_barrier(0);
}

__global__ __launch_bounds__(256) void ttt_scan(
    const float* __restrict__ gXQ, const float* __restrict__ gXK,
    const float* __restrict__ gXV, const float* __restrict__ gETA,
    const float* __restrict__ gW1, const float* __restrict__ gB1,
    const float* __restrict__ gLNW, const float* __restrict__ gLNB,
    float* __restrict__ gOUT)
{
    __shared__ __align__(16) short bxk[16 * 72];   // xk bf16 [s][d]
    __shared__ __align__(16) short bxq[16 * 72];   // xq bf16 [s][d]
    __shared__ __align__(16) short sGt[1024];      // g, K=16 4x16 tr-tiles [jblk][nblk]
    __shared__ __align__(16) short sXKe[1024];     // -le*xk, same tiling
    __shared__ __align__(16) short sE[16 * 20];    // -E [r][j], row stride 20
    __shared__ __align__(16) float sZ1[16 * 68];
    __shared__ __align__(16) float sZb[16 * 68];
    __shared__ __align__(16) float sEta[2][256];   // parity-buffered

    const int t  = threadIdx.x;
    const int s  = t >> 4;
    const int dt = t & 15;
    const int lane = t & 63;
    const int w  = t >> 6;
    const int G  = lane >> 4;
    const int l15 = lane & 15;
    const int bh = blockIdx.x, b = bh >> 3, h = bh & 7;

    const float* xqg = gXQ + (size_t)bh * (NMB * 1024);
    const float* xkg = gXK + (size_t)bh * (NMB * 1024);
    const float* xvg = gXV + (size_t)bh * (NMB * 1024);
    const float* etg = gETA + (size_t)bh * (NMB * 256);

    // W state: wave w owns COLUMNS [16w,16w+16) as 4 k-tile C-fragments.
    // C layout == B layout (k==row) [R13-verified], so WB[kt] feeds MFMA1 directly.
    f32x4 Wacc[4]; short4_t WB[4];
#pragma unroll
    for (int kt = 0; kt < 4; ++kt) {
#pragma unroll
        for (int r = 0; r < 4; ++r)
            Wacc[kt][r] = gW1[h * 4096 + (16 * kt + 4 * G + r) * 64 + 16 * w + l15];
        WB[kt] = pk4(Wacc[kt][0], Wacc[kt][1], Wacc[kt][2], Wacc[kt][3]);
    }
    // b1 state: register, wave w owns col 16w+l15
    float b1v = gB1[h * 64 + 16 * w + l15];

    // LN params in thread layout
    const float4 gam = *(const float4*)&gLNW[h * 64 + dt * 4];
    const float4 bet = *(const float4*)&gLNB[h * 64 + dt * 4];
    const float ga[4] = {gam.x, gam.y, gam.z, gam.w};
    const float ba[4] = {bet.x, bet.y, bet.z, bet.w};
    float c1a[4], gba[4];
    float sc1 = 0.f;
#pragma unroll
    for (int c = 0; c < 4; ++c) {
        c1a[c] = ga[c] * ga[c];
        gba[c] = ga[c] * ba[c];
        sc1 += c1a[c];
    }
    sc1 = dpp16(sc1);

    // ---- prologue: minibatch 0 ----
    float4 pq = *(const float4*)&xqg[t * 4];
    float4 pk = *(const float4*)&xkg[t * 4];
    float4 pv = *(const float4*)&xvg[t * 4];
    float4 pe = make_float4(0.f, 0.f, 0.f, 0.f);
    if (t < 64) pe = *(const float4*)&etg[t * 4];

    { U2S4 u_; u_.u[0]=pkbf(pk.x,pk.y); u_.u[1]=pkbf(pk.z,pk.w);
      *(short4_t*)&bxk[s * 72 + dt * 4] = u_.s; }
    { U2S4 u_; u_.u[0]=pkbf(pq.x,pq.y); u_.u[1]=pkbf(pq.z,pq.w);
      *(short4_t*)&bxq[s * 72 + dt * 4] = u_.s; }
    if (t < 64) *(float4*)&sEta[0][t * 4] = pe;
    float t2c[4];
    float S5c;
    {
        const float pva[4] = {pv.x, pv.y, pv.z, pv.w};
        const float pka_[4] = {pk.x, pk.y, pk.z, pk.w};
        float s5 = 0.f;
#pragma unroll
        for (int c = 0; c < 4; ++c) {
            t2c[c] = fmaf(-ga[c], pva[c] - pka_[c], gba[c]);
            s5 += t2c[c];
        }
        S5c = dpp16(s5);
    }
    float4 pkc = pk;        // xk(m) for phase A's sXKe staging
    float4 pq_out = pq;     // xq(m) for output
    float4 pq_prev_out;

    __syncthreads();

#pragma unroll 1
    for (int m = 0; m < NMB; ++m) {
        const int p = m & 1;

        // ======== PHASE A: MFMA1 + E + deferred output + sXKe staging; prefetch ========
        if (m + 1 < NMB) {
            const size_t o = (size_t)(m + 1) * 1024 + t * 4;
            pq = *(const float4*)&xqg[o];
            pk = *(const float4*)&xkg[o];
            pv = *(const float4*)&xvg[o];
            if (t < 64) pe = *(const float4*)&etg[(size_t)(m + 1) * 256 + t * 4];
        }

        // A-frags: A[m=l15][k=16kt+4G..+3] from bxk/bxq (b64 reads)
        short4_t ak[4], aq[4];
#pragma unroll
        for (int kt = 0; kt < 4; ++kt) {
            ak[kt] = *(const short4_t*)&bxk[l15 * 72 + 16 * kt + 4 * G];
            aq[kt] = *(const short4_t*)&bxq[l15 * 72 + 16 * kt + 4 * G];
        }
        // Z1/Zq n-tile w from register WB (no LDS W!)
        f32x4 z1, zq;
        z1[0]=b1v; z1[1]=b1v; z1[2]=b1v; z1[3]=b1v;
        zq = z1;
#pragma unroll
        for (int kt = 0; kt < 4; ++kt) z1 = MFMA16(ak[kt], WB[kt], z1);
#pragma unroll
        for (int kt = 0; kt < 4; ++kt) zq = MFMA16(aq[kt], WB[kt], zq);
#pragma unroll
        for (int r = 0; r < 4; ++r) sZ1[(4 * G + r) * 68 + 16 * w + l15] = z1[r];

        // wave 3: Attn C-frag -> -E straight to sE
        if (w == 3) {
            f32x4 at; at[0]=0.f; at[1]=0.f; at[2]=0.f; at[3]=0.f;
#pragma unroll
            for (int kt = 0; kt < 4; ++kt) at = MFMA16(aq[kt], ak[kt], at);
#pragma unroll
            for (int r = 0; r < 4; ++r) {
                const int row = 4 * G + r;
                const float ev = sEta[p][row * 16 + l15];
                const float x = (l15 <= row) ? -ev * (1.f + at[r]) : 0.f;
                sE[row * 20 + l15] = bf16s(x);
            }
        }

        // sXKe staging for THIS step (needs only le(m) + pkc regs; read in phase C)
        {
            const float le = sEta[p][240 + s];
            const int tb = (s >> 2) * 256 + (dt >> 2) * 64 + (s & 3) * 16 + (dt & 3) * 4;
            U2S4 kp; kp.u[0]=pkbf(-le*pkc.x,-le*pkc.y); kp.u[1]=pkbf(-le*pkc.z,-le*pkc.w);
            *(short4_t*)&sXKe[tb] = kp.s;
        }

        // deferred LN-fwd + output for step m-1
        if (m > 0) {
            f32x4 zbr = *(f32x4*)&sZb[s * 68 + dt * 4];
            float T1 = 0.f, T2 = 0.f;
#pragma unroll
            for (int c = 0; c < 4; ++c) { T1 += zbr[c]; T2 = fmaf(zbr[c], zbr[c], T2); }
            T1 = dpp16(T1); T2 = dpp16(T2);
            const float mu2   = T1 * (1.f / 64.f);
            const float rstd2 = rsqrtf(T2 * (1.f / 64.f) - mu2 * mu2 + 1e-6f);
            const float pqa[4] = {pq_prev_out.x, pq_prev_out.y, pq_prev_out.z, pq_prev_out.w};
            float o[4];
#pragma unroll
            for (int c = 0; c < 4; ++c)
                o[c] = pqa[c] + fmaf(ga[c], (zbr[c] - mu2) * rstd2, ba[c]);
            const size_t oi = ((size_t)b * 4096 + (size_t)(m - 1) * 16 + s) * 512 + h * 64 + dt * 4;
            *(float4*)&gOUT[oi] = make_float4(o[0], o[1], o[2], o[3]);
        }
        bar();   // (C) sZ1, sE, sXKe visible

        // ======== PHASE B: LN-bwd (DPP 5-sum + carried S5) -> g ; stage g^T ========
        f32x4 z = *(f32x4*)&sZ1[s * 68 + dt * 4];
        float S1=0.f,S2=0.f,S3=0.f,S4=0.f,S6=0.f;
#pragma unroll
        for (int c = 0; c < 4; ++c) {
            const float zc = z[c], c1z = c1a[c] * zc;
            S1 += zc;  S2 = fmaf(zc, zc, S2);
            S3 += c1z; S4 = fmaf(c1z, zc, S4);
            S6 = fmaf(t2c[c], zc, S6);
        }
        S1 = dpp16(S1); S2 = dpp16(S2); S3 = dpp16(S3);
        S4 = dpp16(S4); S6 = dpp16(S6);
        const float mu   = S1 * (1.f / 64.f);
        const float rstd = rsqrtf(S2 * (1.f / 64.f) - mu * mu + 1e-6f);
        const float r1 = rstd * (S3 - mu * sc1) + S5c;
        const float r2 = rstd * rstd * (S4 - 2.f * mu * S3 + mu * mu * sc1)
                       + rstd * (S6 - mu * S5c);
        const float cf = rstd * (1.f / 64.f);
        float g[4];
#pragma unroll
        for (int c = 0; c < 4; ++c) {
            const float xh = (z[c] - mu) * rstd;
            const float gx = fmaf(c1a[c], xh, t2c[c]);
            g[c] = (fmaf(64.f, gx, -r1) - xh * r2) * cf;
        }
        {
            const int tb = (s >> 2) * 256 + (dt >> 2) * 64 + (s & 3) * 16 + (dt & 3) * 4;
            U2S4 gp; gp.u[0]=pkbf(g[0],g[1]); gp.u[1]=pkbf(g[2],g[3]);
            *(short4_t*)&sGt[tb] = gp.s;
        }
        bar();   // (D) sGt visible

        // ======== PHASE C: MFMA2 (W cols in-register) + staging ========
        const unsigned kbX = (unsigned)(size_t)&sXKe[0] + 512u * G + 8u * l15;
        const unsigned kbG = (unsigned)(size_t)&sGt[0] + 512u * G + 128u * (unsigned)w + 8u * l15;
        short4_t aXK0, aXK1, aXK2, aXK3, bg;
        TR_READ(aXK0, kbX, "0");
        TR_READ(aXK1, kbX, "128");
        TR_READ(aXK2, kbX, "256");
        TR_READ(aXK3, kbX, "384");
        TR_READ(bg,   kbG, "0");
        const short4_t aE = *(const short4_t*)&sE[l15 * 20 + 4 * G];
        const f32x4 lv = *(const f32x4*)&sEta[p][240 + 4 * G];
        U2S4 aL;
        aL.u[0] = pkbf(-lv[0], -lv[1]);
        aL.u[1] = pkbf(-lv[2], -lv[3]);
        asm volatile("s_waitcnt lgkmcnt(0)" ::: "memory");
        __builtin_amdgcn_sched_barrier(0);

        Wacc[0] = MFMA16(aXK0, bg, Wacc[0]);
        Wacc[1] = MFMA16(aXK1, bg, Wacc[1]);
        Wacc[2] = MFMA16(aXK2, bg, Wacc[2]);
        Wacc[3] = MFMA16(aXK3, bg, Wacc[3]);
        f32x4 zb = MFMA16(aE, bg, zq);
        {
            f32x4 d0; d0[0]=0.f; d0[1]=0.f; d0[2]=0.f; d0[3]=0.f;
            d0 = MFMA16(aL.s, bg, d0);
            b1v += d0[0];
        }
        // repack W C-frags -> B-frags in registers (no LDS round-trip)
#pragma unroll
        for (int kt = 0; kt < 4; ++kt)
            WB[kt] = pk4(Wacc[kt][0], Wacc[kt][1], Wacc[kt][2], Wacc[kt][3]);
#pragma unroll
        for (int r = 0; r < 4; ++r) sZb[(4 * G + r) * 68 + 16 * w + l15] = zb[r];

        // STAGE(m+1): bxk/bxq/sEta[p^1]/t2c/S5 from prefetched regs
        if (m + 1 < NMB) {
            { U2S4 u_; u_.u[0]=pkbf(pk.x,pk.y); u_.u[1]=pkbf(pk.z,pk.w);
              *(short4_t*)&bxk[s * 72 + dt * 4] = u_.s; }
            { U2S4 u_; u_.u[0]=pkbf(pq.x,pq.y); u_.u[1]=pkbf(pq.z,pq.w);
              *(short4_t*)&bxq[s * 72 + dt * 4] = u_.s; }
            if (t < 64) *(float4*)&sEta[p ^ 1][t * 4] = pe;
            float s5 = 0.f;
#pragma unroll
            for (int c = 0; c < 4; ++c) {
                const float pva[4] = {pv.x, pv.y, pv.z, pv.w};
                const float pka_[4] = {pk.x, pk.y, pk.z, pk.w};
                t2c[c] = fmaf(-ga[c], pva[c] - pka_[c], gba[c]);
                s5 += t2c[c];
            }
            S5c = dpp16(s5);
            pkc = pk;
        }
        pq_prev_out = pq_out;
        pq_out = pq;
        bar();   // (E) sZb/sEta/bxk/bxq visible
    }

    // epilogue: deferred output for m = NMB-1
    {
        f32x4 zbr = *(f32x4*)&sZb[s * 68 + dt * 4];
        float T1 = 0.f, T2 = 0.f;
#pragma unroll
        for (int c = 0; c < 4; ++c) { T1 += zbr[c]; T2 = fmaf(zbr[c], zbr[c], T2); }
        T1 = dpp16(T1); T2 = dpp16(T2);
        const float mu2   = T1 * (1.f / 64.f);
        const float rstd2 = rsqrtf(T2 * (1.f / 64.f) - mu2 * mu2 + 1e-6f);
        const float pqa[4] = {pq_prev_out.x, pq_prev_out.y, pq_prev_out.z, pq_prev_out.w};
        float o[4];
#pragma unroll
        for (int c = 0; c < 4; ++c)
            o[c] = pqa[c] + fmaf(ga[c], (zbr[c] - mu2) * rstd2, ba[c]);
        const size_t oi = ((size_t)b * 4096 + (size_t)(NMB - 1) * 16 + s) * 512 + h * 64 + dt * 4;
        *(float4*)&gOUT[oi] = make_float4(o[0], o[1], o[2], o[3]);
    }
}

extern "C" void kernel_launch(void* const* d_in, const int* in_sizes, int n_in,
                              void* d_out, int out_size, void* d_ws, size_t ws_size,
                              hipStream_t stream) {
    const float* XQ  = (const float*)d_in[0];
    const float* XK  = (const float*)d_in[1];
    const float* XV  = (const float*)d_in[2];
    const float* ETA = (const float*)d_in[3];
    const float* W1  = (const float*)d_in[4];
    const float* B1  = (const float*)d_in[5];
    const float* LNW = (const float*)d_in[6];
    const float* LNB = (const float*)d_in[7];
    float* OUT = (float*)d_out;

    const int n_chains = in_sizes[0] / (NMB * 1024);   // B*nh = 64
    ttt_scan<<<n_chains, 256, 0, stream>>>(XQ, XK, XV, ETA, W1, B1, LNW, LNB, OUT);
}

// Round 15
// 328.118 us; speedup vs baseline: 2.4177x; 1.1476x over previous
//
#include <hip/hip_runtime.h>
#include <hip/hip_bf16.h>

typedef __attribute__((ext_vector_type(4))) short short4_t;
typedef __attribute__((ext_vector_type(4))) float f32x4;

constexpr int NMB = 256;

#if __has_builtin(__builtin_amdgcn_mfma_f32_16x16x16bf16_1k)
#define MFMA16(a, b, c) __builtin_amdgcn_mfma_f32_16x16x16bf16_1k(a, b, c, 0, 0, 0)
#else
__device__ inline f32x4 mfma16_asm(short4_t a, short4_t b, f32x4 c) {
    asm volatile("v_mfma_f32_16x16x16_bf16 %0, %1, %2, %0\n\ts_nop 7\n\ts_nop 7"
                 : "+v"(c) : "v"(a), "v"(b));
    return c;
}
#define MFMA16(a, b, c) mfma16_asm(a, b, c)
#endif

#define TR_READ(dst, addr, IMM) \
    asm volatile("ds_read_b64_tr_b16 %0, %1 offset:" IMM : "=&v"(dst) : "v"(addr) : "memory")

union U2S4 { unsigned u[2]; short4_t s; };
union FI { float f; int i; };

__device__ inline unsigned pkbf(float a, float b) {
    union { __hip_bfloat162 h; unsigned u; } c;
    c.h = __float22bfloat162_rn(make_float2(a, b));
    return c.u;
}
__device__ inline short4_t pk4(float a, float b, float c, float d) {
    U2S4 u; u.u[0] = pkbf(a, b); u.u[1] = pkbf(c, d); return u.s;
}
// all-VALU 16-lane sum reduce: quad_perm xor1, xor2, then row_ror 4, 8
__device__ inline float dpp16(float x) {
    FI v; v.f = x; FI t;
    t.i = __builtin_amdgcn_update_dpp(0, v.i, 0xB1, 0xf, 0xf, true);  v.f += t.f;
    t.i = __builtin_amdgcn_update_dpp(0, v.i, 0x4E, 0xf, 0xf, true);  v.f += t.f;
    t.i = __builtin_amdgcn_update_dpp(0, v.i, 0x124, 0xf, 0xf, true); v.f += t.f;
    t.i = __builtin_amdgcn_update_dpp(0, v.i, 0x128, 0xf, 0xf, true); v.f += t.f;
    return v.f;
}
// raw barrier: LDS writes visible, global loads stay in flight
__device__ inline void bar() {
    __builtin_amdgcn_sched_barrier(0);
    asm volatile("s_waitcnt lgkmcnt(0)" ::: "memory");
    __builtin_amdgcn_s_barrier();
    __builtin_amdgcn_sched_barrier(0);
}

__global__ __launch_bounds__(256) void ttt_scan(
    const float* __restrict__ gXQ, const float* __restrict__ gXK,
    const float* __restrict__ gXV, const float* __restrict__ gETA,
    const float* __restrict__ gW1, const float* __restrict__ gB1,
    const float* __restrict__ gLNW, const float* __restrict__ gLNB,
    float* __restrict__ gOUT)
{
    __shared__ __align__(16) short bxk[16 * 72];   // xk bf16 [s][d]
    __shared__ __align__(16) short bxq[16 * 72];   // xq bf16 [s][d]
    __shared__ __align__(16) short sGt[1024];      // g, K=16 4x16 tr-tiles [jblk][nblk]
    __shared__ __align__(16) short sXKe[1024];     // -le*xk, same tiling
    __shared__ __align__(16) float sZ1[16 * 68];
    __shared__ __align__(16) float sZb[16 * 68];
    __shared__ __align__(16) float sEta[2][256];   // parity-buffered

    const int t  = threadIdx.x;
    const int s  = t >> 4;
    const int dt = t & 15;
    const int lane = t & 63;
    const int w  = t >> 6;
    const int G  = lane >> 4;
    const int l15 = lane & 15;
    const int bh = blockIdx.x, b = bh >> 3, h = bh & 7;

    const float* xqg = gXQ + (size_t)bh * (NMB * 1024);
    const float* xkg = gXK + (size_t)bh * (NMB * 1024);
    const float* xvg = gXV + (size_t)bh * (NMB * 1024);
    const float* etg = gETA + (size_t)bh * (NMB * 256);

    // W state: wave w owns COLUMNS [16w,16w+16) as 4 k-tile C-fragments.
    // C layout == B layout (k==row) [R13-verified]; WB[kt] feeds MFMA1 directly.
    f32x4 Wacc[4]; short4_t WB[4];
#pragma unroll
    for (int kt = 0; kt < 4; ++kt) {
#pragma unroll
        for (int r = 0; r < 4; ++r)
            Wacc[kt][r] = gW1[h * 4096 + (16 * kt + 4 * G + r) * 64 + 16 * w + l15];
        WB[kt] = pk4(Wacc[kt][0], Wacc[kt][1], Wacc[kt][2], Wacc[kt][3]);
    }
    float b1v = gB1[h * 64 + 16 * w + l15];

    // LN params in thread layout
    const float4 gam = *(const float4*)&gLNW[h * 64 + dt * 4];
    const float4 bet = *(const float4*)&gLNB[h * 64 + dt * 4];
    const float ga[4] = {gam.x, gam.y, gam.z, gam.w};
    const float ba[4] = {bet.x, bet.y, bet.z, bet.w};
    float c1a[4], gba[4];
    float sc1 = 0.f;
#pragma unroll
    for (int c = 0; c < 4; ++c) {
        c1a[c] = ga[c] * ga[c];
        gba[c] = ga[c] * ba[c];
        sc1 += c1a[c];
    }
    sc1 = dpp16(sc1);

    // ---- prologue: minibatch 0 ----
    float4 pq = *(const float4*)&xqg[t * 4];
    float4 pk = *(const float4*)&xkg[t * 4];
    float4 pv = *(const float4*)&xvg[t * 4];
    float4 pe = make_float4(0.f, 0.f, 0.f, 0.f);
    if (t < 64) pe = *(const float4*)&etg[t * 4];

    { U2S4 u_; u_.u[0]=pkbf(pk.x,pk.y); u_.u[1]=pkbf(pk.z,pk.w);
      *(short4_t*)&bxk[s * 72 + dt * 4] = u_.s; }
    { U2S4 u_; u_.u[0]=pkbf(pq.x,pq.y); u_.u[1]=pkbf(pq.z,pq.w);
      *(short4_t*)&bxq[s * 72 + dt * 4] = u_.s; }
    if (t < 64) *(float4*)&sEta[0][t * 4] = pe;
    float t2c[4];
    float S5c;
    {
        const float pva[4] = {pv.x, pv.y, pv.z, pv.w};
        const float pka_[4] = {pk.x, pk.y, pk.z, pk.w};
        float s5 = 0.f;
#pragma unroll
        for (int c = 0; c < 4; ++c) {
            t2c[c] = fmaf(-ga[c], pva[c] - pka_[c], gba[c]);
            s5 += t2c[c];
        }
        S5c = dpp16(s5);
    }
    float4 pkc = pk;        // xk(m) for phase A's sXKe staging
    float4 pq_out = pq;     // xq(m) for output
    float4 pq_prev_out;

    __syncthreads();

#pragma unroll 1
    for (int m = 0; m < NMB; ++m) {
        const int p = m & 1;

        // ======== PHASE A: MFMA1 + AttnT + sXKe staging; issue prefetch ========
        if (m + 1 < NMB) {
            const size_t o = (size_t)(m + 1) * 1024 + t * 4;
            pq = *(const float4*)&xqg[o];
            pk = *(const float4*)&xkg[o];
            pv = *(const float4*)&xvg[o];
            if (t < 64) pe = *(const float4*)&etg[(size_t)(m + 1) * 256 + t * 4];
        }

        // A-frags: A[m=l15][k=16kt+4G..+3] from bxk/bxq (b64 reads)
        short4_t ak[4], aq[4];
#pragma unroll
        for (int kt = 0; kt < 4; ++kt) {
            ak[kt] = *(const short4_t*)&bxk[l15 * 72 + 16 * kt + 4 * G];
            aq[kt] = *(const short4_t*)&bxq[l15 * 72 + 16 * kt + 4 * G];
        }
        // Z1/Zq n-tile w from register WB
        f32x4 z1, zq;
        z1[0]=b1v; z1[1]=b1v; z1[2]=b1v; z1[3]=b1v;
        zq = z1;
#pragma unroll
        for (int kt = 0; kt < 4; ++kt) z1 = MFMA16(ak[kt], WB[kt], z1);
#pragma unroll
        for (int kt = 0; kt < 4; ++kt) zq = MFMA16(aq[kt], WB[kt], zq);
#pragma unroll
        for (int r = 0; r < 4; ++r) sZ1[(4 * G + r) * 68 + 16 * w + l15] = z1[r];

        // AttnT = xk @ xq^T (swapped operands): slot i holds Attn[l15][4G+i]
        // -> E A-frag buildable fully in-register in phase C (no sE, no wave-3 skew)
        f32x4 at; at[0]=0.f; at[1]=0.f; at[2]=0.f; at[3]=0.f;
#pragma unroll
        for (int kt = 0; kt < 4; ++kt) at = MFMA16(ak[kt], aq[kt], at);

        // sXKe staging for THIS step (needs only le(m) + pkc regs; read in phase C)
        {
            const float le = sEta[p][240 + s];
            const int tb = (s >> 2) * 256 + (dt >> 2) * 64 + (s & 3) * 16 + (dt & 3) * 4;
            U2S4 kp; kp.u[0]=pkbf(-le*pkc.x,-le*pkc.y); kp.u[1]=pkbf(-le*pkc.z,-le*pkc.w);
            *(short4_t*)&sXKe[tb] = kp.s;
        }
        bar();   // (C) sZ1, sXKe visible

        // ======== PHASE B: LN-bwd -> g ; deferred LN-fwd + output (7 parallel chains) ====
        f32x4 z = *(f32x4*)&sZ1[s * 68 + dt * 4];
        f32x4 zbr;
        if (m > 0) zbr = *(f32x4*)&sZb[s * 68 + dt * 4];
        float S1=0.f,S2=0.f,S3=0.f,S4=0.f,S6=0.f;
#pragma unroll
        for (int c = 0; c < 4; ++c) {
            const float zc = z[c], c1z = c1a[c] * zc;
            S1 += zc;  S2 = fmaf(zc, zc, S2);
            S3 += c1z; S4 = fmaf(c1z, zc, S4);
            S6 = fmaf(t2c[c], zc, S6);
        }
        float T1 = 0.f, T2 = 0.f;
        if (m > 0) {
#pragma unroll
            for (int c = 0; c < 4; ++c) { T1 += zbr[c]; T2 = fmaf(zbr[c], zbr[c], T2); }
        }
        S1 = dpp16(S1); S2 = dpp16(S2); S3 = dpp16(S3);
        S4 = dpp16(S4); S6 = dpp16(S6);
        if (m > 0) { T1 = dpp16(T1); T2 = dpp16(T2); }

        const float mu   = S1 * (1.f / 64.f);
        const float rstd = rsqrtf(S2 * (1.f / 64.f) - mu * mu + 1e-6f);
        const float r1 = rstd * (S3 - mu * sc1) + S5c;
        const float r2 = rstd * rstd * (S4 - 2.f * mu * S3 + mu * mu * sc1)
                       + rstd * (S6 - mu * S5c);
        const float cf = rstd * (1.f / 64.f);
        float g[4];
#pragma unroll
        for (int c = 0; c < 4; ++c) {
            const float xh = (z[c] - mu) * rstd;
            const float gx = fmaf(c1a[c], xh, t2c[c]);
            g[c] = (fmaf(64.f, gx, -r1) - xh * r2) * cf;
        }
        {
            const int tb = (s >> 2) * 256 + (dt >> 2) * 64 + (s & 3) * 16 + (dt & 3) * 4;
            U2S4 gp; gp.u[0]=pkbf(g[0],g[1]); gp.u[1]=pkbf(g[2],g[3]);
            *(short4_t*)&sGt[tb] = gp.s;
        }
        if (m > 0) {
            const float mu2   = T1 * (1.f / 64.f);
            const float rstd2 = rsqrtf(T2 * (1.f / 64.f) - mu2 * mu2 + 1e-6f);
            const float pqa[4] = {pq_prev_out.x, pq_prev_out.y, pq_prev_out.z, pq_prev_out.w};
            float o[4];
#pragma unroll
            for (int c = 0; c < 4; ++c)
                o[c] = pqa[c] + fmaf(ga[c], (zbr[c] - mu2) * rstd2, ba[c]);
            const size_t oi = ((size_t)b * 4096 + (size_t)(m - 1) * 16 + s) * 512 + h * 64 + dt * 4;
            *(float4*)&gOUT[oi] = make_float4(o[0], o[1], o[2], o[3]);
        }
        bar();   // (D) sGt visible

        // ======== PHASE C: MFMA2 (W cols in-register) + staging ========
        const unsigned kbX = (unsigned)(size_t)&sXKe[0] + 512u * G + 8u * l15;
        const unsigned kbG = (unsigned)(size_t)&sGt[0] + 512u * G + 128u * (unsigned)w + 8u * l15;
        short4_t aXK0, aXK1, aXK2, aXK3, bg;
        TR_READ(aXK0, kbX, "0");
        TR_READ(aXK1, kbX, "128");
        TR_READ(aXK2, kbX, "256");
        TR_READ(aXK3, kbX, "384");
        TR_READ(bg,   kbG, "0");
        // aE built in-register from AttnT: slot i = -eta[l15][4G+i]*(1+at[i]) masked tril
        const f32x4 ev4 = *(const f32x4*)&sEta[p][l15 * 16 + 4 * G];
        float ex[4];
#pragma unroll
        for (int i = 0; i < 4; ++i)
            ex[i] = (4 * G + i <= l15) ? -ev4[i] * (1.f + at[i]) : 0.f;
        const short4_t aE = pk4(ex[0], ex[1], ex[2], ex[3]);
        const f32x4 lv = *(const f32x4*)&sEta[p][240 + 4 * G];
        U2S4 aL;
        aL.u[0] = pkbf(-lv[0], -lv[1]);
        aL.u[1] = pkbf(-lv[2], -lv[3]);
        asm volatile("s_waitcnt lgkmcnt(0)" ::: "memory");
        __builtin_amdgcn_sched_barrier(0);

        Wacc[0] = MFMA16(aXK0, bg, Wacc[0]);
        Wacc[1] = MFMA16(aXK1, bg, Wacc[1]);
        Wacc[2] = MFMA16(aXK2, bg, Wacc[2]);
        Wacc[3] = MFMA16(aXK3, bg, Wacc[3]);
        f32x4 zb = MFMA16(aE, bg, zq);
        {
            f32x4 d0; d0[0]=0.f; d0[1]=0.f; d0[2]=0.f; d0[3]=0.f;
            d0 = MFMA16(aL.s, bg, d0);
            b1v += d0[0];
        }
        // repack W C-frags -> B-frags in registers
#pragma unroll
        for (int kt = 0; kt < 4; ++kt)
            WB[kt] = pk4(Wacc[kt][0], Wacc[kt][1], Wacc[kt][2], Wacc[kt][3]);
#pragma unroll
        for (int r = 0; r < 4; ++r) sZb[(4 * G + r) * 68 + 16 * w + l15] = zb[r];

        // STAGE(m+1): bxk/bxq/sEta[p^1]/t2c/S5 from prefetched regs
        if (m + 1 < NMB) {
            { U2S4 u_; u_.u[0]=pkbf(pk.x,pk.y); u_.u[1]=pkbf(pk.z,pk.w);
              *(short4_t*)&bxk[s * 72 + dt * 4] = u_.s; }
            { U2S4 u_; u_.u[0]=pkbf(pq.x,pq.y); u_.u[1]=pkbf(pq.z,pq.w);
              *(short4_t*)&bxq[s * 72 + dt * 4] = u_.s; }
            if (t < 64) *(float4*)&sEta[p ^ 1][t * 4] = pe;
            float s5 = 0.f;
#pragma unroll
            for (int c = 0; c < 4; ++c) {
                const float pva[4] = {pv.x, pv.y, pv.z, pv.w};
                const float pka_[4] = {pk.x, pk.y, pk.z, pk.w};
                t2c[c] = fmaf(-ga[c], pva[c] - pka_[c], gba[c]);
                s5 += t2c[c];
            }
            S5c = dpp16(s5);
            pkc = pk;
        }
        pq_prev_out = pq_out;
        pq_out = pq;
        bar();   // (E) sZb/sEta/bxk/bxq visible
    }

    // epilogue: deferred output for m = NMB-1
    {
        f32x4 zbr = *(f32x4*)&sZb[s * 68 + dt * 4];
        float T1 = 0.f, T2 = 0.f;
#pragma unroll
        for (int c = 0; c < 4; ++c) { T1 += zbr[c]; T2 = fmaf(zbr[c], zbr[c], T2); }
        T1 = dpp16(T1); T2 = dpp16(T2);
        const float mu2   = T1 * (1.f / 64.f);
        const float rstd2 = rsqrtf(T2 * (1.f / 64.f) - mu2 * mu2 + 1e-6f);
        const float pqa[4] = {pq_prev_out.x, pq_prev_out.y, pq_prev_out.z, pq_prev_out.w};
        float o[4];
#pragma unroll
        for (int c = 0; c < 4; ++c)
            o[c] = pqa[c] + fmaf(ga[c], (zbr[c] - mu2) * rstd2, ba[c]);
        const size_t oi = ((size_t)b * 4096 + (size_t)(NMB - 1) * 16 + s) * 512 + h * 64 + dt * 4;
        *(float4*)&gOUT[oi] = make_float4(o[0], o[1], o[2], o[3]);
    }
}

extern "C" void kernel_launch(void* const* d_in, const int* in_sizes, int n_in,
                              void* d_out, int out_size, void* d_ws, size_t ws_size,
                              hipStream_t stream) {
    const float* XQ  = (const float*)d_in[0];
    const float* XK  = (const float*)d_in[1];
    const float* XV  = (const float*)d_in[2];
    const float* ETA = (const float*)d_in[3];
    const float* W1  = (const float*)d_in[4];
    const float* B1  = (const float*)d_in[5];
    const float* LNW = (const float*)d_in[6];
    const float* LNB = (const float*)d_in[7];
    float* OUT = (float*)d_out;

    const int n_chains = in_sizes[0] / (NMB * 1024);   // B*nh = 64
    ttt_scan<<<n_chains, 256, 0, stream>>>(XQ, XK, XV, ETA, W1, B1, LNW, LNB, OUT);
}